// Round 1
// baseline (696.897 us; speedup 1.0000x reference)
//
#include <hip/hip_runtime.h>
#include <hip/hip_bf16.h>
#include <stdint.h>

#define T_DIM 10000
#define B_DIM 32
#define L_DIM 128
#define D_DIM 256
#define NT_TILES 79          // ceil(10000/128)
#define TPAD (NT_TILES*128)  // 10112

typedef __bf16 bf16x8 __attribute__((ext_vector_type(8)));
typedef float  f32x4  __attribute__((ext_vector_type(4)));
typedef unsigned short us8 __attribute__((ext_vector_type(8)));
typedef unsigned short ushort_t;

__device__ __forceinline__ unsigned short f2bf(float f){
  union { float f; uint32_t u; } v; v.f = f;
  uint32_t u = v.u;
  return (unsigned short)((u + 0x7fffu + ((u >> 16) & 1u)) >> 16);  // RNE
}

__device__ __forceinline__ void async16(const void* g, void* l){
  __builtin_amdgcn_global_load_lds((const __attribute__((address_space(1))) void*)g,
                                   (__attribute__((address_space(3))) void*)l,
                                   16, 0, 0);
}

__device__ __forceinline__ float fast_tanh(float x){
  x = fminf(8.f, fmaxf(-8.f, x));
  float e = __expf(2.f * x);
  return (e - 1.f) * __builtin_amdgcn_rcpf(e + 1.f);
}

// --- P0: event_enc = emb_table[event_type] -> bf16 [4096][256] -------------
__global__ __launch_bounds__(64) void k_gather_emb(const float* __restrict__ emb,
    const int* __restrict__ et, ushort_t* __restrict__ ebf){
  int r = blockIdx.x;           // 0..4095 (b*128+l)
  int d4 = threadIdx.x;         // 0..63
  int e = et[r];
  float4 v = *((const float4*)(emb + (size_t)e * D_DIM) + d4);
  ushort4 o; o.x = f2bf(v.x); o.y = f2bf(v.y); o.z = f2bf(v.z); o.w = f2bf(v.w);
  *((ushort4*)(ebf + (size_t)r * D_DIM) + d4) = o;
}

// --- P1: W5 -> bf16, zero-padded to TPAD rows ------------------------------
__global__ __launch_bounds__(64) void k_conv_w5(const float* __restrict__ W5,
                                                ushort_t* __restrict__ w5b){
  int t = blockIdx.x;           // 0..TPAD-1
  int d4 = threadIdx.x;
  ushort4 o = {0,0,0,0};
  if (t < T_DIM){
    float4 v = *((const float4*)(W5 + (size_t)t * D_DIM) + d4);
    o.x = f2bf(v.x); o.y = f2bf(v.y); o.z = f2bf(v.z); o.w = f2bf(v.w);
  }
  *((ushort4*)(w5b + (size_t)t * D_DIM) + d4) = o;
}

// --- dm = mean(data, axis=1) -> bf16 [32][256] -----------------------------
__global__ __launch_bounds__(256) void k_dm(const float* __restrict__ data,
                                            ushort_t* __restrict__ dmb){
  int b = blockIdx.x, d = threadIdx.x;
  const float* p = data + (size_t)b * L_DIM * D_DIM + d;
  float s = 0.f;
  #pragma unroll 4
  for (int l = 0; l < L_DIM; l++) s += p[(size_t)l * D_DIM];
  dmb[b * D_DIM + d] = f2bf(s * (1.0f / L_DIM));
}

// --- fused: tanh(enc·W5ᵀ)·drop·corr, reduce over L -> item [32][10000] -----
__global__ __launch_bounds__(256) void k_big(
    const ushort_t* __restrict__ ebf, const ushort_t* __restrict__ w5b,
    const float* __restrict__ corr, const float* __restrict__ drop,
    const int* __restrict__ et, float* __restrict__ item){
  __shared__ __align__(16) ushort_t lA[128 * 128];  // 32KB: A chunk [l][k]
  __shared__ __align__(16) ushort_t lB[128 * 128];  // 32KB: B chunk [t][k]
  const int b  = blockIdx.y;
  const int t0 = blockIdx.x * 128;
  const int tid = threadIdx.x;
  const int w = tid >> 6, lane = tid & 63, col = lane & 15, quad = lane >> 4;

  f32x4 zero4 = {0.f, 0.f, 0.f, 0.f};
  f32x4 acc[2][8];
  #pragma unroll
  for (int m = 0; m < 2; m++)
    #pragma unroll
    for (int n = 0; n < 8; n++) acc[m][n] = zero4;

  for (int c = 0; c < 2; c++){                 // K chunks of 128
    if (c) __syncthreads();
    // stage: LDS slot (row, s) holds global segment s^(row&7) (16B segs)
    #pragma unroll
    for (int r = 0; r < 8; r++){
      int row = r * 16 + w * 4 + quad;
      int gseg = col ^ (row & 7);
      async16(ebf + (size_t)(b * L_DIM + row) * D_DIM + c * 128 + gseg * 8,
              lA + (r * 16 + w * 4) * 128);
      async16(w5b + (size_t)(t0 + row) * D_DIM + c * 128 + gseg * 8,
              lB + (r * 16 + w * 4) * 128);
    }
    __syncthreads();
    #pragma unroll
    for (int kk = 0; kk < 4; kk++){
      bf16x8 af[2];
      #pragma unroll
      for (int m = 0; m < 2; m++){
        int row = (w * 2 + m) * 16 + col;
        int sg = (kk * 4 + quad) ^ (row & 7);
        af[m] = *(const bf16x8*)(lA + row * 128 + sg * 8);
      }
      #pragma unroll
      for (int n = 0; n < 8; n++){
        int row = n * 16 + col;
        int sg = (kk * 4 + quad) ^ (row & 7);
        bf16x8 bf = *(const bf16x8*)(lB + row * 128 + sg * 8);
        acc[0][n] = __builtin_amdgcn_mfma_f32_16x16x32_bf16(af[0], bf, acc[0][n], 0, 0, 0);
        acc[1][n] = __builtin_amdgcn_mfma_f32_16x16x32_bf16(af[1], bf, acc[1][n], 0, 0, 0);
      }
    }
  }
  __syncthreads();

  // epilogue: each lane owns rows l=(2w+m)*16+quad*4+j, cols t0+n*16+col
  const float* dptr[8]; const float* cptr[8]; float vm[8];
  #pragma unroll
  for (int m = 0; m < 2; m++)
    #pragma unroll
    for (int j = 0; j < 4; j++){
      int i = m * 4 + j;
      int l = (w * 2 + m) * 16 + quad * 4 + j;
      int e = et[b * L_DIM + l];
      dptr[i] = drop + (size_t)(b * L_DIM + l) * T_DIM;
      cptr[i] = corr + (size_t)(e > 0 ? e - 1 : 0) * T_DIM;
      vm[i] = (e > 0) ? 1.f : 0.f;
    }

  float* red = (float*)lA;  // reuse LDS: [4 waves][128 t]
  #pragma unroll
  for (int n = 0; n < 8; n++){
    int t = t0 + n * 16 + col;
    bool tv = t < T_DIM;
    float s = 0.f;
    #pragma unroll
    for (int m = 0; m < 2; m++)
      #pragma unroll
      for (int j = 0; j < 4; j++){
        int i = m * 4 + j;
        float th = fast_tanh(acc[m][n][j]);
        float dv = tv ? dptr[i][t] : 0.f;
        float cv = tv ? cptr[i][t] : 0.f;
        s += th * dv * (cv * vm[i]);
      }
    s += __shfl_xor(s, 16);
    s += __shfl_xor(s, 32);
    if (lane < 16) red[w * 128 + n * 16 + col] = s;
  }
  __syncthreads();
  if (tid < 128){
    int t = t0 + tid;
    if (t < T_DIM)
      item[(size_t)b * T_DIM + t] = red[tid] + red[128 + tid] + red[256 + tid] + red[384 + tid];
  }
}

// --- q[k][b][t] = dm[b]·Wk[t] via MFMA, in-kernel f32->bf16 staging --------
__global__ __launch_bounds__(256) void k_qgemm(
    const float* __restrict__ W1, const float* __restrict__ W2,
    const float* __restrict__ W3, const float* __restrict__ W4,
    const ushort_t* __restrict__ dmb, float* __restrict__ q){
  __shared__ __align__(16) ushort_t lB[128 * 128];
  const int kw = blockIdx.y;
  const float* W = (kw == 0) ? W1 : (kw == 1) ? W2 : (kw == 2) ? W3 : W4;
  const int t0 = blockIdx.x * 128;
  const int tid = threadIdx.x;
  const int w = tid >> 6, lane = tid & 63, col = lane & 15, quad = lane >> 4;

  f32x4 zero4 = {0.f, 0.f, 0.f, 0.f};
  f32x4 acc[2][2];
  acc[0][0] = zero4; acc[0][1] = zero4; acc[1][0] = zero4; acc[1][1] = zero4;

  for (int c = 0; c < 2; c++){
    if (c) __syncthreads();
    #pragma unroll
    for (int it = 0; it < 8; it++){
      int idx = it * 256 + tid;
      int row = idx >> 4, slot = idx & 15;
      int gseg = slot ^ (row & 7);
      int t = t0 + row;
      float4 u0 = {0,0,0,0}, u1 = {0,0,0,0};
      if (t < T_DIM){
        const float* gp = W + (size_t)t * D_DIM + c * 128 + gseg * 8;
        u0 = *(const float4*)gp;
        u1 = *(const float4*)(gp + 4);
      }
      us8 o;
      o[0] = f2bf(u0.x); o[1] = f2bf(u0.y); o[2] = f2bf(u0.z); o[3] = f2bf(u0.w);
      o[4] = f2bf(u1.x); o[5] = f2bf(u1.y); o[6] = f2bf(u1.z); o[7] = f2bf(u1.w);
      *(us8*)(lB + row * 128 + slot * 8) = o;
    }
    __syncthreads();
    #pragma unroll
    for (int kk = 0; kk < 4; kk++){
      int kabs = c * 128 + kk * 32 + quad * 8;
      bf16x8 af[2];
      #pragma unroll
      for (int m = 0; m < 2; m++)
        af[m] = *(const bf16x8*)(dmb + (size_t)(m * 16 + col) * D_DIM + kabs);
      #pragma unroll
      for (int n2 = 0; n2 < 2; n2++){
        int row = (w * 2 + n2) * 16 + col;
        int sg = (kk * 4 + quad) ^ (row & 7);
        bf16x8 bf = *(const bf16x8*)(lB + row * 128 + sg * 8);
        acc[0][n2] = __builtin_amdgcn_mfma_f32_16x16x32_bf16(af[0], bf, acc[0][n2], 0, 0, 0);
        acc[1][n2] = __builtin_amdgcn_mfma_f32_16x16x32_bf16(af[1], bf, acc[1][n2], 0, 0, 0);
      }
    }
  }
  #pragma unroll
  for (int m = 0; m < 2; m++)
    #pragma unroll
    for (int n2 = 0; n2 < 2; n2++)
      #pragma unroll
      for (int j = 0; j < 4; j++){
        int brow = m * 16 + quad * 4 + j;
        int t = t0 + (w * 2 + n2) * 16 + col;
        if (t < T_DIM)
          q[((size_t)kw * B_DIM + brow) * T_DIM + t] = acc[m][n2][j];
      }
}

// --- norms[which][b]: which 0..3 = q_k, which 4 = item ---------------------
__global__ __launch_bounds__(256) void k_norms(const float* __restrict__ q,
    const float* __restrict__ item, float* __restrict__ norms){
  int which = blockIdx.x, b = blockIdx.y;
  const float* src = (which < 4) ? (q + ((size_t)which * B_DIM + b) * T_DIM)
                                 : (item + (size_t)b * T_DIM);
  float s = 0.f;
  for (int i = threadIdx.x; i < T_DIM; i += 256){ float v = src[i]; s = fmaf(v, v, s); }
  #pragma unroll
  for (int o = 1; o < 64; o <<= 1) s += __shfl_xor(s, o);
  __shared__ float tmp[4];
  if ((threadIdx.x & 63) == 0) tmp[threadIdx.x >> 6] = s;
  __syncthreads();
  if (threadIdx.x == 0) norms[which * B_DIM + b] = sqrtf(tmp[0] + tmp[1] + tmp[2] + tmp[3]);
}

// --- final combine + target fill -------------------------------------------
__global__ __launch_bounds__(256) void k_final(
    const float* __restrict__ q, const float* __restrict__ item,
    const float* __restrict__ norms,
    const float* __restrict__ pa, const float* __restrict__ pb,
    const float* __restrict__ pc, const float* __restrict__ pd,
    float* __restrict__ out, float* __restrict__ tgt){
  int b = blockIdx.y;
  int t = blockIdx.x * 256 + threadIdx.x;
  if (t >= T_DIM) return;
  float coef0 = *pa, coef1 = *pb, coef2 = *pc, coef3 = *pd;
  float v = item[(size_t)b * T_DIM + t] / fmaxf(norms[4 * B_DIM + b], 1e-5f);
  v += q[((size_t)0 * B_DIM + b) * T_DIM + t] * coef0 / fmaxf(norms[0 * B_DIM + b], 1e-5f);
  v += q[((size_t)1 * B_DIM + b) * T_DIM + t] * coef1 / fmaxf(norms[1 * B_DIM + b], 1e-5f);
  v += q[((size_t)2 * B_DIM + b) * T_DIM + t] * coef2 / fmaxf(norms[2 * B_DIM + b], 1e-5f);
  v += q[((size_t)3 * B_DIM + b) * T_DIM + t] * coef3 / fmaxf(norms[3 * B_DIM + b], 1e-5f);
  out[(size_t)b * T_DIM + t] = tanhf(v);
  tgt[(size_t)b * T_DIM + t] = 1.0f;
}

// --- target scatter: zeros at observed event indices -----------------------
__global__ __launch_bounds__(256) void k_scatter(const int* __restrict__ et,
                                                 float* __restrict__ tgt){
  int i = blockIdx.x * 256 + threadIdx.x;
  if (i < B_DIM * L_DIM){
    int e = et[i];
    if (e > 0) tgt[(size_t)(i >> 7) * T_DIM + (e - 1)] = 0.f;
  }
}

extern "C" void kernel_launch(void* const* d_in, const int* in_sizes, int n_in,
                              void* d_out, int out_size, void* d_ws, size_t ws_size,
                              hipStream_t stream){
  const float* data = (const float*)d_in[0];
  const int*   et   = (const int*)d_in[1];
  const float* emb  = (const float*)d_in[2];
  const float* corr = (const float*)d_in[3];
  const float* W1   = (const float*)d_in[4];
  const float* W2   = (const float*)d_in[5];
  const float* W3   = (const float*)d_in[6];
  const float* W4   = (const float*)d_in[7];
  const float* W5   = (const float*)d_in[8];
  const float* ca   = (const float*)d_in[9];
  const float* cb   = (const float*)d_in[10];
  const float* cc   = (const float*)d_in[11];
  const float* cd   = (const float*)d_in[12];
  const float* drop = (const float*)d_in[13];

  char* p = (char*)d_ws;
  ushort_t* ebf  = (ushort_t*)p; p += (size_t)B_DIM * L_DIM * D_DIM * 2;  // 2 MB
  ushort_t* w5b  = (ushort_t*)p; p += (size_t)TPAD * D_DIM * 2;           // ~5.2 MB
  ushort_t* dmb  = (ushort_t*)p; p += (size_t)B_DIM * D_DIM * 2;          // 16 KB
  float*    q    = (float*)p;    p += (size_t)4 * B_DIM * T_DIM * 4;      // 5.12 MB
  float*    item = (float*)p;    p += (size_t)B_DIM * T_DIM * 4;          // 1.28 MB
  float*    norms= (float*)p;    p += (size_t)5 * B_DIM * 4;

  float* out = (float*)d_out;
  float* tgt = out + (size_t)B_DIM * T_DIM;

  hipLaunchKernelGGL(k_gather_emb, dim3(B_DIM * L_DIM), dim3(64), 0, stream, emb, et, ebf);
  hipLaunchKernelGGL(k_conv_w5,    dim3(TPAD),          dim3(64), 0, stream, W5, w5b);
  hipLaunchKernelGGL(k_dm,         dim3(B_DIM),         dim3(256), 0, stream, data, dmb);
  hipLaunchKernelGGL(k_big,        dim3(NT_TILES, B_DIM), dim3(256), 0, stream,
                     ebf, w5b, corr, drop, et, item);
  hipLaunchKernelGGL(k_qgemm,      dim3(NT_TILES, 4),   dim3(256), 0, stream,
                     W1, W2, W3, W4, dmb, q);
  hipLaunchKernelGGL(k_norms,      dim3(5, B_DIM),      dim3(256), 0, stream, q, item, norms);
  hipLaunchKernelGGL(k_final,      dim3(40, B_DIM),     dim3(256), 0, stream,
                     q, item, norms, ca, cb, cc, cd, out, tgt);
  hipLaunchKernelGGL(k_scatter,    dim3(16),            dim3(256), 0, stream, et, tgt);
}

// Round 2
// 693.090 us; speedup vs baseline: 1.0055x; 1.0055x over previous
//
#include <hip/hip_runtime.h>
#include <hip/hip_bf16.h>
#include <stdint.h>

#define T_DIM 10000
#define B_DIM 32
#define L_DIM 128
#define D_DIM 256
#define NT_TILES 79          // ceil(10000/128)
#define TPAD (NT_TILES*128)  // 10112

typedef __bf16 bf16x8 __attribute__((ext_vector_type(8)));
typedef float  f32x4  __attribute__((ext_vector_type(4)));
typedef unsigned short us8 __attribute__((ext_vector_type(8)));
typedef unsigned short ushort_t;

__device__ __forceinline__ unsigned short f2bf(float f){
  union { float f; uint32_t u; } v; v.f = f;
  uint32_t u = v.u;
  return (unsigned short)((u + 0x7fffu + ((u >> 16) & 1u)) >> 16);  // RNE
}

__device__ __forceinline__ void async16(const void* g, void* l){
  __builtin_amdgcn_global_load_lds((const __attribute__((address_space(1))) void*)g,
                                   (__attribute__((address_space(3))) void*)l,
                                   16, 0, 0);
}

__device__ __forceinline__ float fast_tanh(float x){
  x = fminf(8.f, fmaxf(-8.f, x));
  float e = __expf(2.f * x);
  return (e - 1.f) * __builtin_amdgcn_rcpf(e + 1.f);
}

// --- fused prep: emb gather->bf16, W5->bf16 (padded), dm, tgt=1 ------------
// grid layout: [0,1024) emb | [1024,3552) w5 | [3552,3584) dm | [3584,4834) tgt
__global__ __launch_bounds__(256) void k_prep(
    const float* __restrict__ emb, const int* __restrict__ et,
    const float* __restrict__ W5, const float* __restrict__ data,
    ushort_t* __restrict__ ebf, ushort_t* __restrict__ w5b,
    ushort_t* __restrict__ dmb, float* __restrict__ tgt){
  int bx = blockIdx.x, tid = threadIdx.x;
  if (bx < 1024){                       // event_enc gather: 4096 rows
    int r = bx * 4 + (tid >> 6), d4 = tid & 63;
    int e = et[r];
    float4 v = *((const float4*)(emb + (size_t)e * D_DIM) + d4);
    ushort4 o; o.x = f2bf(v.x); o.y = f2bf(v.y); o.z = f2bf(v.z); o.w = f2bf(v.w);
    *((ushort4*)(ebf + (size_t)r * D_DIM) + d4) = o;
  } else if (bx < 3552){                // W5 convert: 10112 rows (zero-pad tail)
    int r = (bx - 1024) * 4 + (tid >> 6), d4 = tid & 63;
    ushort4 o = {0,0,0,0};
    if (r < T_DIM){
      float4 v = *((const float4*)(W5 + (size_t)r * D_DIM) + d4);
      o.x = f2bf(v.x); o.y = f2bf(v.y); o.z = f2bf(v.z); o.w = f2bf(v.w);
    }
    *((ushort4*)(w5b + (size_t)r * D_DIM) + d4) = o;
  } else if (bx < 3584){                // dm = mean(data, axis=1)
    int b = bx - 3552, d = tid;
    const float* p = data + (size_t)b * L_DIM * D_DIM + d;
    float s = 0.f;
    #pragma unroll 4
    for (int l = 0; l < L_DIM; l++) s += p[(size_t)l * D_DIM];
    dmb[b * D_DIM + d] = f2bf(s * (1.0f / L_DIM));
  } else {                              // tgt = 1.0
    int i = (bx - 3584) * 256 + tid;
    if (i < B_DIM * T_DIM) tgt[i] = 1.0f;
  }
}

// --- fused: tanh(enc·W5ᵀ)·drop·corr, reduce over L -> item [32][10000] -----
// v2: K-chunk 64 -> 32KB LDS, 4 blocks/CU target (was 64KB / 2 blocks/CU)
__global__ __launch_bounds__(256, 4) void k_big(
    const ushort_t* __restrict__ ebf, const ushort_t* __restrict__ w5b,
    const float* __restrict__ corr, const float* __restrict__ drop,
    const int* __restrict__ et, float* __restrict__ item){
  __shared__ __align__(16) ushort_t lA[128 * 64];  // 16KB: A chunk [l][k64]
  __shared__ __align__(16) ushort_t lB[128 * 64];  // 16KB: B chunk [t][k64]
  const int b  = blockIdx.y;
  const int t0 = blockIdx.x * 128;
  const int tid = threadIdx.x;
  const int w = tid >> 6, lane = tid & 63, col = lane & 15, quad = lane >> 4;
  const int srow8 = lane >> 3, sslot = lane & 7;   // staging lane decomposition

  f32x4 zero4 = {0.f, 0.f, 0.f, 0.f};
  f32x4 acc[2][8];
  #pragma unroll
  for (int m = 0; m < 2; m++)
    #pragma unroll
    for (int n = 0; n < 8; n++) acc[m][n] = zero4;

  for (int c = 0; c < 4; c++){                 // K chunks of 64
    if (c) __syncthreads();
    // stage: LDS slot (row, s) holds global 16B segment s^(row&7)
    #pragma unroll
    for (int it = 0; it < 4; it++){
      int rb = (it * 4 + w) * 8;               // wave-uniform row base
      int row = rb + srow8;
      int gseg = sslot ^ (row & 7);
      async16(ebf + (size_t)(b * L_DIM + row) * D_DIM + c * 64 + gseg * 8,
              lA + rb * 64);
      async16(w5b + (size_t)(t0 + row) * D_DIM + c * 64 + gseg * 8,
              lB + rb * 64);
    }
    __syncthreads();
    #pragma unroll
    for (int kk = 0; kk < 2; kk++){
      bf16x8 af[2];
      #pragma unroll
      for (int m = 0; m < 2; m++){
        int row = w * 32 + m * 16 + col;
        int sg = (kk * 4 + quad) ^ (row & 7);
        af[m] = *(const bf16x8*)(lA + row * 64 + sg * 8);
      }
      #pragma unroll
      for (int n = 0; n < 8; n++){
        int row = n * 16 + col;
        int sg = (kk * 4 + quad) ^ (row & 7);
        bf16x8 bf = *(const bf16x8*)(lB + row * 64 + sg * 8);
        acc[0][n] = __builtin_amdgcn_mfma_f32_16x16x32_bf16(af[0], bf, acc[0][n], 0, 0, 0);
        acc[1][n] = __builtin_amdgcn_mfma_f32_16x16x32_bf16(af[1], bf, acc[1][n], 0, 0, 0);
      }
    }
  }
  __syncthreads();

  // epilogue: lane owns rows l = w*32 + m*16 + quad*4 + j, cols t0 + n*16 + col
  int doff[8]; int coff[8]; float vm[8];
  #pragma unroll
  for (int m = 0; m < 2; m++)
    #pragma unroll
    for (int j = 0; j < 4; j++){
      int i = m * 4 + j;
      int l = w * 32 + m * 16 + quad * 4 + j;
      int e = et[b * L_DIM + l];
      doff[i] = (b * L_DIM + l) * T_DIM;
      coff[i] = (e > 0 ? e - 1 : 0) * T_DIM;
      vm[i] = (e > 0) ? 1.f : 0.f;
    }

  float* red = (float*)lA;  // reuse LDS: [4 waves][128 t]
  #pragma unroll
  for (int n = 0; n < 8; n++){
    int t = t0 + n * 16 + col;
    bool tv = t < T_DIM;
    float s = 0.f;
    #pragma unroll
    for (int m = 0; m < 2; m++)
      #pragma unroll
      for (int j = 0; j < 4; j++){
        int i = m * 4 + j;
        float th = fast_tanh(acc[m][n][j]);
        float dv = tv ? drop[(size_t)doff[i] + t] : 0.f;
        float cv = tv ? corr[(size_t)coff[i] + t] : 0.f;
        s += th * dv * (cv * vm[i]);
      }
    s += __shfl_xor(s, 16);
    s += __shfl_xor(s, 32);
    if (lane < 16) red[w * 128 + n * 16 + col] = s;
  }
  __syncthreads();
  if (tid < 128){
    int t = t0 + tid;
    if (t < T_DIM)
      item[(size_t)b * T_DIM + t] = red[tid] + red[128 + tid] + red[256 + tid] + red[384 + tid];
  }
}

// --- q[k][b][t] = dm[b]·Wk[t] via MFMA, in-kernel f32->bf16 staging --------
__global__ __launch_bounds__(256) void k_qgemm(
    const float* __restrict__ W1, const float* __restrict__ W2,
    const float* __restrict__ W3, const float* __restrict__ W4,
    const ushort_t* __restrict__ dmb, float* __restrict__ q){
  __shared__ __align__(16) ushort_t lB[128 * 128];
  const int kw = blockIdx.y;
  const float* W = (kw == 0) ? W1 : (kw == 1) ? W2 : (kw == 2) ? W3 : W4;
  const int t0 = blockIdx.x * 128;
  const int tid = threadIdx.x;
  const int w = tid >> 6, lane = tid & 63, col = lane & 15, quad = lane >> 4;

  f32x4 zero4 = {0.f, 0.f, 0.f, 0.f};
  f32x4 acc[2][2];
  acc[0][0] = zero4; acc[0][1] = zero4; acc[1][0] = zero4; acc[1][1] = zero4;

  for (int c = 0; c < 2; c++){
    if (c) __syncthreads();
    #pragma unroll
    for (int it = 0; it < 8; it++){
      int idx = it * 256 + tid;
      int row = idx >> 4, slot = idx & 15;
      int gseg = slot ^ (row & 7);
      int t = t0 + row;
      float4 u0 = {0,0,0,0}, u1 = {0,0,0,0};
      if (t < T_DIM){
        const float* gp = W + (size_t)t * D_DIM + c * 128 + gseg * 8;
        u0 = *(const float4*)gp;
        u1 = *(const float4*)(gp + 4);
      }
      us8 o;
      o[0] = f2bf(u0.x); o[1] = f2bf(u0.y); o[2] = f2bf(u0.z); o[3] = f2bf(u0.w);
      o[4] = f2bf(u1.x); o[5] = f2bf(u1.y); o[6] = f2bf(u1.z); o[7] = f2bf(u1.w);
      *(us8*)(lB + row * 128 + slot * 8) = o;
    }
    __syncthreads();
    #pragma unroll
    for (int kk = 0; kk < 4; kk++){
      int kabs = c * 128 + kk * 32 + quad * 8;
      bf16x8 af[2];
      #pragma unroll
      for (int m = 0; m < 2; m++)
        af[m] = *(const bf16x8*)(dmb + (size_t)(m * 16 + col) * D_DIM + kabs);
      #pragma unroll
      for (int n2 = 0; n2 < 2; n2++){
        int row = (w * 2 + n2) * 16 + col;
        int sg = (kk * 4 + quad) ^ (row & 7);
        bf16x8 bf = *(const bf16x8*)(lB + row * 128 + sg * 8);
        acc[0][n2] = __builtin_amdgcn_mfma_f32_16x16x32_bf16(af[0], bf, acc[0][n2], 0, 0, 0);
        acc[1][n2] = __builtin_amdgcn_mfma_f32_16x16x32_bf16(af[1], bf, acc[1][n2], 0, 0, 0);
      }
    }
  }
  #pragma unroll
  for (int m = 0; m < 2; m++)
    #pragma unroll
    for (int n2 = 0; n2 < 2; n2++)
      #pragma unroll
      for (int j = 0; j < 4; j++){
        int brow = m * 16 + quad * 4 + j;
        int t = t0 + (w * 2 + n2) * 16 + col;
        if (t < T_DIM)
          q[((size_t)kw * B_DIM + brow) * T_DIM + t] = acc[m][n2][j];
      }
}

// --- norms[which][b] (which 0..4) + target scatter (which==5) --------------
__global__ __launch_bounds__(256) void k_norms(const float* __restrict__ q,
    const float* __restrict__ item, float* __restrict__ norms,
    const int* __restrict__ et, float* __restrict__ tgt){
  int which = blockIdx.x, b = blockIdx.y;
  if (which == 5){                      // scatter zeros into tgt (tgt=1 from k_prep)
    if (threadIdx.x < L_DIM){
      int e = et[b * L_DIM + threadIdx.x];
      if (e > 0) tgt[(size_t)b * T_DIM + (e - 1)] = 0.f;
    }
    return;
  }
  const float* src = (which < 4) ? (q + ((size_t)which * B_DIM + b) * T_DIM)
                                 : (item + (size_t)b * T_DIM);
  float s = 0.f;
  for (int i = threadIdx.x; i < T_DIM; i += 256){ float v = src[i]; s = fmaf(v, v, s); }
  #pragma unroll
  for (int o = 1; o < 64; o <<= 1) s += __shfl_xor(s, o);
  __shared__ float tmp[4];
  if ((threadIdx.x & 63) == 0) tmp[threadIdx.x >> 6] = s;
  __syncthreads();
  if (threadIdx.x == 0) norms[which * B_DIM + b] = sqrtf(tmp[0] + tmp[1] + tmp[2] + tmp[3]);
}

// --- final combine --------------------------------------------------------
__global__ __launch_bounds__(256) void k_final(
    const float* __restrict__ q, const float* __restrict__ item,
    const float* __restrict__ norms,
    const float* __restrict__ pa, const float* __restrict__ pb,
    const float* __restrict__ pc, const float* __restrict__ pd,
    float* __restrict__ out){
  int b = blockIdx.y;
  int t = blockIdx.x * 256 + threadIdx.x;
  if (t >= T_DIM) return;
  float coef0 = *pa, coef1 = *pb, coef2 = *pc, coef3 = *pd;
  float v = item[(size_t)b * T_DIM + t] / fmaxf(norms[4 * B_DIM + b], 1e-5f);
  v += q[((size_t)0 * B_DIM + b) * T_DIM + t] * coef0 / fmaxf(norms[0 * B_DIM + b], 1e-5f);
  v += q[((size_t)1 * B_DIM + b) * T_DIM + t] * coef1 / fmaxf(norms[1 * B_DIM + b], 1e-5f);
  v += q[((size_t)2 * B_DIM + b) * T_DIM + t] * coef2 / fmaxf(norms[2 * B_DIM + b], 1e-5f);
  v += q[((size_t)3 * B_DIM + b) * T_DIM + t] * coef3 / fmaxf(norms[3 * B_DIM + b], 1e-5f);
  out[(size_t)b * T_DIM + t] = tanhf(v);
}

extern "C" void kernel_launch(void* const* d_in, const int* in_sizes, int n_in,
                              void* d_out, int out_size, void* d_ws, size_t ws_size,
                              hipStream_t stream){
  const float* data = (const float*)d_in[0];
  const int*   et   = (const int*)d_in[1];
  const float* emb  = (const float*)d_in[2];
  const float* corr = (const float*)d_in[3];
  const float* W1   = (const float*)d_in[4];
  const float* W2   = (const float*)d_in[5];
  const float* W3   = (const float*)d_in[6];
  const float* W4   = (const float*)d_in[7];
  const float* W5   = (const float*)d_in[8];
  const float* ca   = (const float*)d_in[9];
  const float* cb   = (const float*)d_in[10];
  const float* cc   = (const float*)d_in[11];
  const float* cd   = (const float*)d_in[12];
  const float* drop = (const float*)d_in[13];

  char* p = (char*)d_ws;
  ushort_t* ebf  = (ushort_t*)p; p += (size_t)B_DIM * L_DIM * D_DIM * 2;  // 2 MB
  ushort_t* w5b  = (ushort_t*)p; p += (size_t)TPAD * D_DIM * 2;           // ~5.2 MB
  ushort_t* dmb  = (ushort_t*)p; p += (size_t)B_DIM * D_DIM * 2;          // 16 KB
  float*    q    = (float*)p;    p += (size_t)4 * B_DIM * T_DIM * 4;      // 5.12 MB
  float*    item = (float*)p;    p += (size_t)B_DIM * T_DIM * 4;          // 1.28 MB
  float*    norms= (float*)p;    p += (size_t)5 * B_DIM * 4;

  float* out = (float*)d_out;
  float* tgt = out + (size_t)B_DIM * T_DIM;

  hipLaunchKernelGGL(k_prep,  dim3(4834),            dim3(256), 0, stream,
                     emb, et, W5, data, ebf, w5b, dmb, tgt);
  hipLaunchKernelGGL(k_big,   dim3(NT_TILES, B_DIM), dim3(256), 0, stream,
                     ebf, w5b, corr, drop, et, item);
  hipLaunchKernelGGL(k_qgemm, dim3(NT_TILES, 4),     dim3(256), 0, stream,
                     W1, W2, W3, W4, dmb, q);
  hipLaunchKernelGGL(k_norms, dim3(6, B_DIM),        dim3(256), 0, stream,
                     q, item, norms, et, tgt);
  hipLaunchKernelGGL(k_final, dim3(40, B_DIM),       dim3(256), 0, stream,
                     q, item, norms, ca, cb, cc, cd, out);
}

// Round 4
// 688.192 us; speedup vs baseline: 1.0127x; 1.0071x over previous
//
#include <hip/hip_runtime.h>
#include <hip/hip_bf16.h>
#include <stdint.h>

#define T_DIM 10000
#define B_DIM 32
#define L_DIM 128
#define D_DIM 256
#define NT_TILES 79          // ceil(10000/128)
#define TPAD (NT_TILES*128)  // 10112

typedef __bf16 bf16x8 __attribute__((ext_vector_type(8)));
typedef float  f32x4  __attribute__((ext_vector_type(4)));
typedef unsigned short us8 __attribute__((ext_vector_type(8)));
typedef unsigned short ushort_t;

__device__ __forceinline__ unsigned short f2bf(float f){
  union { float f; uint32_t u; } v; v.f = f;
  uint32_t u = v.u;
  return (unsigned short)((u + 0x7fffu + ((u >> 16) & 1u)) >> 16);  // RNE
}

__device__ __forceinline__ void async16(const void* g, void* l){
  __builtin_amdgcn_global_load_lds((const __attribute__((address_space(1))) void*)g,
                                   (__attribute__((address_space(3))) void*)l,
                                   16, 0, 0);
}

__device__ __forceinline__ float fast_tanh(float x){
  x = fminf(8.f, fmaxf(-8.f, x));
  float e = __expf(2.f * x);
  return (e - 1.f) * __builtin_amdgcn_rcpf(e + 1.f);
}

// --- fused prep: emb gather->bf16, W5->bf16 (padded), dm, tgt=1, norms2=0 --
// grid: [0,1024) emb | [1024,3552) w5 | [3552,3584) dm | [3584,4834) tgt | 4834 zero
__global__ __launch_bounds__(256) void k_prep(
    const float* __restrict__ emb, const int* __restrict__ et,
    const float* __restrict__ W5, const float* __restrict__ data,
    ushort_t* __restrict__ ebf, ushort_t* __restrict__ w5b,
    ushort_t* __restrict__ dmb, float* __restrict__ tgt,
    float* __restrict__ norms2){
  int bx = blockIdx.x, tid = threadIdx.x;
  if (bx < 1024){                       // event_enc gather: 4096 rows
    int r = bx * 4 + (tid >> 6), d4 = tid & 63;
    int e = et[r];
    float4 v = *((const float4*)(emb + (size_t)e * D_DIM) + d4);
    ushort4 o; o.x = f2bf(v.x); o.y = f2bf(v.y); o.z = f2bf(v.z); o.w = f2bf(v.w);
    *((ushort4*)(ebf + (size_t)r * D_DIM) + d4) = o;
  } else if (bx < 3552){                // W5 convert: 10112 rows (zero-pad tail)
    int r = (bx - 1024) * 4 + (tid >> 6), d4 = tid & 63;
    ushort4 o = {0,0,0,0};
    if (r < T_DIM){
      float4 v = *((const float4*)(W5 + (size_t)r * D_DIM) + d4);
      o.x = f2bf(v.x); o.y = f2bf(v.y); o.z = f2bf(v.z); o.w = f2bf(v.w);
    }
    *((ushort4*)(w5b + (size_t)r * D_DIM) + d4) = o;
  } else if (bx < 3584){                // dm = mean(data, axis=1)
    int b = bx - 3552, d = tid;
    const float* p = data + (size_t)b * L_DIM * D_DIM + d;
    float s = 0.f;
    #pragma unroll 4
    for (int l = 0; l < L_DIM; l++) s += p[(size_t)l * D_DIM];
    dmb[b * D_DIM + d] = f2bf(s * (1.0f / L_DIM));
  } else if (bx < 4834){                // tgt = 1.0
    int i = (bx - 3584) * 256 + tid;
    if (i < B_DIM * T_DIM) tgt[i] = 1.0f;
  } else {                              // norms2 = 0 (160 floats)
    if (tid < 160) norms2[tid] = 0.f;
  }
}

// --- merged: blockIdx.y<32 -> k_big path; y in [32,36) -> qgemm path -------
// big:  tanh(enc·W5ᵀ)·drop·corr, reduce L -> item[b,t]; + atomic ss(item)
// qgemm: q[kw][b][t] = dm[b]·Wkw[t]; + atomic ss(q_kw[b])
__global__ __launch_bounds__(256, 4) void k_main(
    const ushort_t* __restrict__ ebf, const ushort_t* __restrict__ w5b,
    const float* __restrict__ corr, const float* __restrict__ drop,
    const int* __restrict__ et, float* __restrict__ item,
    const float* __restrict__ W1, const float* __restrict__ W2,
    const float* __restrict__ W3, const float* __restrict__ W4,
    const ushort_t* __restrict__ dmb, float* __restrict__ q,
    float* __restrict__ norms2){
  __shared__ __align__(16) ushort_t smem[128 * 128];  // 32KB (union of paths)
  __shared__ float ssq[32];
  const int t0 = blockIdx.x * 128;
  const int tid = threadIdx.x;
  const int w = tid >> 6, lane = tid & 63, col = lane & 15, quad = lane >> 4;

  if (blockIdx.y < B_DIM){
    // ---------------- big path ----------------
    ushort_t* lA = smem;                 // [128][64] bf16, 16KB
    ushort_t* lB = smem + 128 * 64;      // [128][64] bf16, 16KB
    const int b = blockIdx.y;
    const int srow8 = lane >> 3, sslot = lane & 7;

    f32x4 zero4 = {0.f, 0.f, 0.f, 0.f};
    f32x4 acc[2][8];
    #pragma unroll
    for (int m = 0; m < 2; m++)
      #pragma unroll
      for (int n = 0; n < 8; n++) acc[m][n] = zero4;

    for (int c = 0; c < 4; c++){                 // K chunks of 64
      if (c) __syncthreads();
      #pragma unroll
      for (int it = 0; it < 4; it++){
        int rb = (it * 4 + w) * 8;               // wave-uniform row base
        int row = rb + srow8;
        int gseg = sslot ^ (row & 7);
        async16(ebf + (size_t)(b * L_DIM + row) * D_DIM + c * 64 + gseg * 8,
                lA + rb * 64);
        async16(w5b + (size_t)(t0 + row) * D_DIM + c * 64 + gseg * 8,
                lB + rb * 64);
      }
      __syncthreads();
      #pragma unroll
      for (int kk = 0; kk < 2; kk++){
        bf16x8 af[2];
        #pragma unroll
        for (int m = 0; m < 2; m++){
          int row = w * 32 + m * 16 + col;
          int sg = (kk * 4 + quad) ^ (row & 7);
          af[m] = *(const bf16x8*)(lA + row * 64 + sg * 8);
        }
        #pragma unroll
        for (int n = 0; n < 8; n++){
          int row = n * 16 + col;
          int sg = (kk * 4 + quad) ^ (row & 7);
          bf16x8 bf = *(const bf16x8*)(lB + row * 64 + sg * 8);
          acc[0][n] = __builtin_amdgcn_mfma_f32_16x16x32_bf16(af[0], bf, acc[0][n], 0, 0, 0);
          acc[1][n] = __builtin_amdgcn_mfma_f32_16x16x32_bf16(af[1], bf, acc[1][n], 0, 0, 0);
        }
      }
    }
    __syncthreads();

    // epilogue: lane owns rows l = w*32 + m*16 + quad*4 + j, cols t0+n*16+col
    int doff[8]; int coff[8]; float vm[8];
    #pragma unroll
    for (int m = 0; m < 2; m++)
      #pragma unroll
      for (int j = 0; j < 4; j++){
        int i = m * 4 + j;
        int l = w * 32 + m * 16 + quad * 4 + j;
        int e = et[b * L_DIM + l];
        doff[i] = (b * L_DIM + l) * T_DIM;
        coff[i] = (e > 0 ? e - 1 : 0) * T_DIM;
        vm[i] = (e > 0) ? 1.f : 0.f;
      }

    float* red = (float*)smem;  // reuse LDS: [4 waves][128 t]
    #pragma unroll
    for (int n = 0; n < 8; n++){
      int t = t0 + n * 16 + col;
      bool tv = t < T_DIM;
      float s = 0.f;
      #pragma unroll
      for (int m = 0; m < 2; m++)
        #pragma unroll
        for (int j = 0; j < 4; j++){
          int i = m * 4 + j;
          float th = fast_tanh(acc[m][n][j]);
          float dv = tv ? drop[(size_t)doff[i] + t] : 0.f;
          float cv = tv ? corr[(size_t)coff[i] + t] : 0.f;
          s += th * dv * (cv * vm[i]);
        }
      s += __shfl_xor(s, 16);
      s += __shfl_xor(s, 32);
      if (lane < 16) red[w * 128 + n * 16 + col] = s;
    }
    __syncthreads();
    float sv = 0.f;
    if (tid < 128){
      int t = t0 + tid;
      if (t < T_DIM){
        float v = red[tid] + red[128 + tid] + red[256 + tid] + red[384 + tid];
        item[(size_t)b * T_DIM + t] = v;
        sv = v * v;
      }
    }
    // block-partial sum of squares -> norms2[128+b]
    #pragma unroll
    for (int o = 1; o < 64; o <<= 1) sv += __shfl_xor(sv, o);
    if (lane == 0 && sv != 0.f) atomicAdd(&norms2[128 + b], sv);
  } else {
    // ---------------- qgemm path ----------------
    ushort_t* lB = smem;                 // [128][128] bf16, 32KB
    const int kw = blockIdx.y - B_DIM;
    const float* W = (kw == 0) ? W1 : (kw == 1) ? W2 : (kw == 2) ? W3 : W4;

    f32x4 zero4 = {0.f, 0.f, 0.f, 0.f};
    f32x4 acc[2][2];
    acc[0][0] = zero4; acc[0][1] = zero4; acc[1][0] = zero4; acc[1][1] = zero4;
    if (tid < 32) ssq[tid] = 0.f;

    for (int c = 0; c < 2; c++){
      if (c) __syncthreads();
      #pragma unroll
      for (int it = 0; it < 8; it++){
        int idx = it * 256 + tid;
        int row = idx >> 4, slot = idx & 15;
        int gseg = slot ^ (row & 7);
        int t = t0 + row;
        float4 u0 = {0,0,0,0}, u1 = {0,0,0,0};
        if (t < T_DIM){
          const float* gp = W + (size_t)t * D_DIM + c * 128 + gseg * 8;
          u0 = *(const float4*)gp;
          u1 = *(const float4*)(gp + 4);
        }
        us8 o;
        o[0] = f2bf(u0.x); o[1] = f2bf(u0.y); o[2] = f2bf(u0.z); o[3] = f2bf(u0.w);
        o[4] = f2bf(u1.x); o[5] = f2bf(u1.y); o[6] = f2bf(u1.z); o[7] = f2bf(u1.w);
        *(us8*)(lB + row * 128 + slot * 8) = o;
      }
      __syncthreads();
      #pragma unroll
      for (int kk = 0; kk < 4; kk++){
        int kabs = c * 128 + kk * 32 + quad * 8;
        bf16x8 af[2];
        #pragma unroll
        for (int m = 0; m < 2; m++)
          af[m] = *(const bf16x8*)(dmb + (size_t)(m * 16 + col) * D_DIM + kabs);
        #pragma unroll
        for (int n2 = 0; n2 < 2; n2++){
          int row = (w * 2 + n2) * 16 + col;
          int sg = (kk * 4 + quad) ^ (row & 7);
          bf16x8 bf = *(const bf16x8*)(lB + row * 128 + sg * 8);
          acc[0][n2] = __builtin_amdgcn_mfma_f32_16x16x32_bf16(af[0], bf, acc[0][n2], 0, 0, 0);
          acc[1][n2] = __builtin_amdgcn_mfma_f32_16x16x32_bf16(af[1], bf, acc[1][n2], 0, 0, 0);
        }
      }
    }
    __syncthreads();   // ssq zero + lB reads complete
    #pragma unroll
    for (int m = 0; m < 2; m++)
      #pragma unroll
      for (int n2 = 0; n2 < 2; n2++)
        #pragma unroll
        for (int j = 0; j < 4; j++){
          int brow = m * 16 + quad * 4 + j;
          int t = t0 + (w * 2 + n2) * 16 + col;
          if (t < T_DIM){
            float v = acc[m][n2][j];
            q[((size_t)kw * B_DIM + brow) * T_DIM + t] = v;
            atomicAdd(&ssq[brow], v * v);
          }
        }
    __syncthreads();
    if (tid < 32) atomicAdd(&norms2[kw * 32 + tid], ssq[tid]);
  }
}

// --- final combine (x<40) + target scatter (x==40) -------------------------
__global__ __launch_bounds__(256) void k_final(
    const float* __restrict__ q, const float* __restrict__ item,
    const float* __restrict__ norms2,
    const float* __restrict__ pa, const float* __restrict__ pb,
    const float* __restrict__ pc, const float* __restrict__ pd,
    float* __restrict__ out, float* __restrict__ tgt,
    const int* __restrict__ et){
  int b = blockIdx.y;
  if (blockIdx.x == 40){                // scatter zeros into tgt
    if (threadIdx.x < L_DIM){
      int e = et[b * L_DIM + threadIdx.x];
      if (e > 0) tgt[(size_t)b * T_DIM + (e - 1)] = 0.f;
    }
    return;
  }
  int t = blockIdx.x * 256 + threadIdx.x;
  if (t >= T_DIM) return;
  float coef[4] = {*pa, *pb, *pc, *pd};
  float v = item[(size_t)b * T_DIM + t] / fmaxf(sqrtf(norms2[128 + b]), 1e-5f);
  #pragma unroll
  for (int k = 0; k < 4; k++)
    v += q[((size_t)k * B_DIM + b) * T_DIM + t] * coef[k]
         / fmaxf(sqrtf(norms2[k * 32 + b]), 1e-5f);
  out[(size_t)b * T_DIM + t] = tanhf(v);
}

extern "C" void kernel_launch(void* const* d_in, const int* in_sizes, int n_in,
                              void* d_out, int out_size, void* d_ws, size_t ws_size,
                              hipStream_t stream){
  const float* data = (const float*)d_in[0];
  const int*   et   = (const int*)d_in[1];
  const float* emb  = (const float*)d_in[2];
  const float* corr = (const float*)d_in[3];
  const float* W1   = (const float*)d_in[4];
  const float* W2   = (const float*)d_in[5];
  const float* W3   = (const float*)d_in[6];
  const float* W4   = (const float*)d_in[7];
  const float* W5   = (const float*)d_in[8];
  const float* ca   = (const float*)d_in[9];
  const float* cb   = (const float*)d_in[10];
  const float* cc   = (const float*)d_in[11];
  const float* cd   = (const float*)d_in[12];
  const float* drop = (const float*)d_in[13];

  char* p = (char*)d_ws;
  ushort_t* ebf  = (ushort_t*)p; p += (size_t)B_DIM * L_DIM * D_DIM * 2;  // 2 MB
  ushort_t* w5b  = (ushort_t*)p; p += (size_t)TPAD * D_DIM * 2;           // ~5.2 MB
  ushort_t* dmb  = (ushort_t*)p; p += (size_t)B_DIM * D_DIM * 2;          // 16 KB
  float*    q    = (float*)p;    p += (size_t)4 * B_DIM * T_DIM * 4;      // 5.12 MB
  float*    item = (float*)p;    p += (size_t)B_DIM * T_DIM * 4;          // 1.28 MB
  float*    norms2=(float*)p;    p += (size_t)160 * 4;                    // ss: [0,128)=q, [128,160)=item

  float* out = (float*)d_out;
  float* tgt = out + (size_t)B_DIM * T_DIM;

  hipLaunchKernelGGL(k_prep,  dim3(4835),                dim3(256), 0, stream,
                     emb, et, W5, data, ebf, w5b, dmb, tgt, norms2);
  hipLaunchKernelGGL(k_main,  dim3(NT_TILES, B_DIM + 4), dim3(256), 0, stream,
                     ebf, w5b, corr, drop, et, item, W1, W2, W3, W4, dmb, q, norms2);
  hipLaunchKernelGGL(k_final, dim3(41, B_DIM),           dim3(256), 0, stream,
                     q, item, norms2, ca, cb, cc, cd, out, tgt, et);
}